// Round 1
// baseline (322.531 us; speedup 1.0000x reference)
//
#include <hip/hip_runtime.h>

// Conv2d NCHW, stride=1, pad=1, N=16, C=8, K=8, H=W=1024, 3x3, fp32.
// One block = 256-wide W stripe x R output rows x all 8 output channels.
// Each thread: one w column, R rows, acc[8][R] in VGPRs.
// Weights indexed wave-uniformly -> scalar loads -> SGPR operand in v_fma_f32.

#define R 4
#define HH 1024
#define WW 1024
#define CI 8
#define CO 8

__global__ __launch_bounds__(256) void conv3x3_kernel(
    const float* __restrict__ x,      // [16][8][1024][1024]
    const float* __restrict__ wgt,    // [8][8][3][3]
    const float* __restrict__ bias,   // [8]
    float* __restrict__ out)          // [16][8][1024][1024]
{
    const int w  = blockIdx.x * 256 + threadIdx.x;   // 0..1023
    const int h0 = blockIdx.y * R;                   // 0..1020
    const int n  = blockIdx.z;                       // 0..15

    const long HW = (long)HH * WW;
    const float* xn = x + (long)n * CI * HW;

    float acc[CO][R];
#pragma unroll
    for (int co = 0; co < CO; ++co) {
        const float b = bias[co];   // uniform -> s_load
#pragma unroll
        for (int r = 0; r < R; ++r) acc[co][r] = b;
    }

    for (int ci = 0; ci < CI; ++ci) {   // NOT unrolled: keeps code small, ci uniform
        const float* xc = xn + (long)ci * HW;

        // Load 6 input rows x 3 shifted columns into registers (zero-padded).
        float in[R + 2][3];
#pragma unroll
        for (int r = 0; r < R + 2; ++r) {
            const int h = h0 - 1 + r;
            const bool hv = (h >= 0) && (h < HH);    // block-uniform
            const float* row = xc + (long)h * WW;
#pragma unroll
            for (int c = 0; c < 3; ++c) {
                const int wc = w - 1 + c;
                const bool v = hv && (wc >= 0) && (wc < WW);
                in[r][c] = v ? row[wc] : 0.0f;
            }
        }

        // 8 output channels x R rows x 9 taps.
#pragma unroll
        for (int co = 0; co < CO; ++co) {
            const float* wp = wgt + ((co * CI + ci) * 9);
            float wv[9];
#pragma unroll
            for (int k = 0; k < 9; ++k) wv[k] = wp[k];   // uniform -> s_load
#pragma unroll
            for (int r = 0; r < R; ++r) {
#pragma unroll
                for (int kh = 0; kh < 3; ++kh) {
#pragma unroll
                    for (int kw = 0; kw < 3; ++kw) {
                        acc[co][r] = fmaf(in[r + kh][kw], wv[kh * 3 + kw], acc[co][r]);
                    }
                }
            }
        }
    }

    // Store: coalesced along w.
#pragma unroll
    for (int co = 0; co < CO; ++co) {
        float* op = out + ((long)n * CO + co) * HW + (long)h0 * WW + w;
#pragma unroll
        for (int r = 0; r < R; ++r) {
            op[(long)r * WW] = acc[co][r];
        }
    }
}

extern "C" void kernel_launch(void* const* d_in, const int* in_sizes, int n_in,
                              void* d_out, int out_size, void* d_ws, size_t ws_size,
                              hipStream_t stream) {
    const float* x    = (const float*)d_in[0];
    const float* wgt  = (const float*)d_in[1];
    const float* bias = (const float*)d_in[2];
    float* out = (float*)d_out;

    dim3 grid(WW / 256, HH / R, 16);   // (4, 256, 16)
    dim3 block(256, 1, 1);
    conv3x3_kernel<<<grid, block, 0, stream>>>(x, wgt, bias, out);
}